// Round 2
// baseline (1352.979 us; speedup 1.0000x reference)
//
#include <hip/hip_runtime.h>

// Submanifold sparse conv 3x3x3, G=128, Cin=Cout=32, fp32.
// Structure: memset table -> scatter (atomicMax: last-write-wins to match
// numpy duplicate semantics) -> conv (32 lanes per point, lane = out channel).

#define GRID 128
#define CIN 32
#define COUT 32
#define NOFF 27

__global__ void scatter_kernel(const int* __restrict__ pos,
                               int* __restrict__ table, int N) {
    int i = blockIdx.x * blockDim.x + threadIdx.x;
    if (i >= N) return;
    int x = pos[3 * i], y = pos[3 * i + 1], z = pos[3 * i + 2];
    // Duplicate voxel coords exist (~60k for N=500k in 128^3). Reference
    // (numpy sequential scatter) keeps the LAST index, i.e. the max.
    atomicMax(&table[(x * GRID + y) * GRID + z], i);
}

__global__ void conv_kernel(const float* __restrict__ feats,
                            const int* __restrict__ pos,
                            const float* __restrict__ wt,
                            const int* __restrict__ table,
                            float* __restrict__ out, int N) {
    int gid = blockIdx.x * blockDim.x + threadIdx.x;
    int pt = gid >> 5;        // 32 threads per point
    int c  = gid & 31;        // output channel
    if (pt >= N) return;

    int x = pos[3 * pt], y = pos[3 * pt + 1], z = pos[3 * pt + 2];

    float acc = 0.0f;
    for (int k = 0; k < NOFF; ++k) {
        int dx = k / 9 - 1;
        int dy = (k / 3) % 3 - 1;
        int dz = k % 3 - 1;
        int nx = x + dx, ny = y + dy, nz = z + dz;
        if ((unsigned)nx < GRID && (unsigned)ny < GRID && (unsigned)nz < GRID) {
            int idx = table[(nx * GRID + ny) * GRID + nz];
            if (idx >= 0) {
                const float* __restrict__ f = feats + (size_t)idx * CIN;
                const float* __restrict__ w = wt + k * (CIN * COUT) + c;
#pragma unroll
                for (int ci = 0; ci < CIN; ++ci) {
                    acc = fmaf(f[ci], w[ci * COUT], acc);
                }
            }
        }
    }
    out[(size_t)pt * COUT + c] = acc;
}

extern "C" void kernel_launch(void* const* d_in, const int* in_sizes, int n_in,
                              void* d_out, int out_size, void* d_ws, size_t ws_size,
                              hipStream_t stream) {
    const float* feats = (const float*)d_in[0];   // [N, 32]
    const int*   pos   = (const int*)d_in[1];     // [N, 3]
    const float* wt    = (const float*)d_in[2];   // [27, 32, 32]
    float* out = (float*)d_out;                   // [N, 32]
    int N = in_sizes[0] / CIN;

    int* table = (int*)d_ws;                      // G^3 int32 = 8 MB
    size_t table_bytes = (size_t)GRID * GRID * GRID * sizeof(int);

    // table = -1 everywhere (0xFF bytes == -1 as int32)
    hipMemsetAsync(table, 0xFF, table_bytes, stream);

    int sb = 256;
    scatter_kernel<<<(N + sb - 1) / sb, sb, 0, stream>>>(pos, table, N);

    long long total = (long long)N * COUT;
    conv_kernel<<<(int)((total + 255) / 256), 256, 0, stream>>>(
        feats, pos, wt, table, out, N);
}

// Round 3
// 452.817 us; speedup vs baseline: 2.9879x; 2.9879x over previous
//
#include <hip/hip_runtime.h>

// Submanifold sparse conv 3x3x3, G=128, Cin=Cout=32.
// R3: implicit-GEMM. One wave per 16-point tile; per offset gather A-frag
// (bf16) directly in MFMA layout, B = W^T staged bf16 in LDS, 2x
// mfma_f32_16x16x32_bf16 accumulate the [16x32] tile.

#define GRID 128
#define CIN 32
#define COUT 32
#define NOFF 27
#define TILE 16
#define WPB 4                 // waves per block
#define BLOCK (WPB * 64)
#define WROW 40               // padded ushort stride per W^T row (80 B -> 2-way banks, free)
#define LDSW (NOFF * COUT * WROW)

typedef __attribute__((ext_vector_type(8))) short bf16x8;
typedef __attribute__((ext_vector_type(4))) float f32x4;

__device__ inline unsigned short f2bf(float x) {
    union { float f; unsigned u; } v; v.f = x;
    unsigned r = v.u + 0x7fff + ((v.u >> 16) & 1);   // RTNE
    return (unsigned short)(r >> 16);
}

__global__ void scatter_kernel(const int* __restrict__ pos,
                               int* __restrict__ table, int N) {
    int i = blockIdx.x * blockDim.x + threadIdx.x;
    if (i >= N) return;
    int x = pos[3 * i], y = pos[3 * i + 1], z = pos[3 * i + 2];
    // numpy duplicate semantics: last write (max index) wins
    atomicMax(&table[(x * GRID + y) * GRID + z], i);
}

// wt [27][ci][co] fp32 -> wtT [27][co][ci] bf16 (B^T rows contiguous in ci)
__global__ void convert_wt(const float* __restrict__ wt,
                           unsigned short* __restrict__ wtT) {
    int t = blockIdx.x * 256 + threadIdx.x;
    if (t >= NOFF * CIN * COUT) return;
    int k = t >> 10, r = t & 1023, ci = r >> 5, co = r & 31;
    wtT[k * 1024 + co * 32 + ci] = f2bf(wt[t]);
}

__global__ __launch_bounds__(BLOCK, 2)
void conv_kernel(const float* __restrict__ feats,
                 const int* __restrict__ pos,
                 const unsigned short* __restrict__ wtT,
                 const int* __restrict__ table,
                 float* __restrict__ out, int N, int numTiles) {
    __shared__ unsigned short ldsw[LDSW];          // 69120 B
    __shared__ int idxs[WPB * NOFF * TILE];        // 6912 B

    int tid = threadIdx.x;

    // Stage W^T bf16 into LDS with +8-ushort row padding (pairs stay aligned).
    const unsigned* w32 = (const unsigned*)wtT;
    for (int e = tid; e < NOFF * 1024 / 2; e += BLOCK) {
        int i2 = e * 2;
        int k = i2 >> 10, r = i2 & 1023, co = r >> 5, ci = r & 31;
        *(unsigned*)&ldsw[k * (COUT * WROW) + co * WROW + ci] = w32[e];
    }
    __syncthreads();

    int wave = tid >> 6, lane = tid & 63;
    int tile = blockIdx.x * WPB + wave;
    if (tile >= numTiles) return;
    int base = tile * TILE;
    int* myidx = &idxs[wave * NOFF * TILE];

    // Precompute neighbor indices for this tile: 27 offsets x 16 points.
    for (int e = lane; e < NOFF * TILE; e += 64) {
        int m = e & 15, k = e >> 4;
        int g = base + m;
        int id = -1;
        if (g < N) {
            int x = pos[3 * g], y = pos[3 * g + 1], z = pos[3 * g + 2];
            int dx = k / 9 - 1, dy = (k / 3) % 3 - 1, dz = k % 3 - 1;
            int nx = x + dx, ny = y + dy, nz = z + dz;
            if ((unsigned)nx < GRID && (unsigned)ny < GRID && (unsigned)nz < GRID)
                id = table[(nx * GRID + ny) * GRID + nz];
        }
        myidx[e] = id;
    }

    int m = lane & 15, quad = lane >> 4;
    f32x4 acc0 = {0.f, 0.f, 0.f, 0.f};
    f32x4 acc1 = {0.f, 0.f, 0.f, 0.f};
    // B-frag LDS base: co = m (frag0) / m+16 (frag1), k-chunk = quad*8
    const unsigned short* wb0 = &ldsw[m * WROW + quad * 8];
    const unsigned short* wb1 = &ldsw[(m + 16) * WROW + quad * 8];

    for (int k = 0; k < NOFF; ++k) {
        int id = myidx[k * 16 + m];
        float4 f0 = {0.f, 0.f, 0.f, 0.f}, f1 = {0.f, 0.f, 0.f, 0.f};
        if (id >= 0) {
            const float* f = feats + (size_t)id * CIN + quad * 8;
            f0 = *(const float4*)f;
            f1 = *(const float4*)(f + 4);
        }
        union { bf16x8 v; unsigned short s[8]; } a;
        a.s[0] = f2bf(f0.x); a.s[1] = f2bf(f0.y);
        a.s[2] = f2bf(f0.z); a.s[3] = f2bf(f0.w);
        a.s[4] = f2bf(f1.x); a.s[5] = f2bf(f1.y);
        a.s[6] = f2bf(f1.z); a.s[7] = f2bf(f1.w);

        bf16x8 b0 = *(const bf16x8*)&wb0[k * (COUT * WROW)];
        bf16x8 b1 = *(const bf16x8*)&wb1[k * (COUT * WROW)];

        acc0 = __builtin_amdgcn_mfma_f32_16x16x32_bf16(a.v, b0, acc0, 0, 0, 0);
        acc1 = __builtin_amdgcn_mfma_f32_16x16x32_bf16(a.v, b1, acc1, 0, 0, 0);
    }

    // D layout: col = lane&15 = co, row = quad*4 + i = point within tile
#pragma unroll
    for (int i = 0; i < 4; ++i) {
        int g = base + quad * 4 + i;
        if (g < N) {
            out[(size_t)g * COUT + m]      = acc0[i];
            out[(size_t)g * COUT + m + 16] = acc1[i];
        }
    }
}

extern "C" void kernel_launch(void* const* d_in, const int* in_sizes, int n_in,
                              void* d_out, int out_size, void* d_ws, size_t ws_size,
                              hipStream_t stream) {
    const float* feats = (const float*)d_in[0];   // [N, 32]
    const int*   pos   = (const int*)d_in[1];     // [N, 3]
    const float* wt    = (const float*)d_in[2];   // [27, 32, 32]
    float* out = (float*)d_out;                   // [N, 32]
    int N = in_sizes[0] / CIN;

    int* table = (int*)d_ws;                      // 8 MB
    size_t table_bytes = (size_t)GRID * GRID * GRID * sizeof(int);
    unsigned short* wtT = (unsigned short*)((char*)d_ws + table_bytes); // 55296 B

    hipMemsetAsync(table, 0xFF, table_bytes, stream);

    int sb = 256;
    scatter_kernel<<<(N + sb - 1) / sb, sb, 0, stream>>>(pos, table, N);

    int wtElems = NOFF * CIN * COUT;
    convert_wt<<<(wtElems + 255) / 256, 256, 0, stream>>>(wt, wtT);

    int numTiles = (N + TILE - 1) / TILE;
    int blocks = (numTiles + WPB - 1) / WPB;
    conv_kernel<<<blocks, BLOCK, 0, stream>>>(feats, pos, wtT, table, out, N, numTiles);
}

// Round 4
// 317.113 us; speedup vs baseline: 4.2666x; 1.4279x over previous
//
#include <hip/hip_runtime.h>

// Submanifold sparse conv 3x3x3, G=128, Cin=Cout=32.
// R4: no-LDS implicit GEMM. Pre-convert feats+weights to bf16. One wave per
// 16-point tile; per offset k (fully unrolled): inline table lookup, 16B bf16
// A-frag gather, coalesced global B-frag loads (L2-hot), 2x
// mfma_f32_16x16x32_bf16. launch_bounds(256,5) -> ~20 waves/CU.

#define GRID 128
#define CIN 32
#define COUT 32
#define NOFF 27
#define TILE 16

typedef __attribute__((ext_vector_type(8))) short bf16x8;
typedef __attribute__((ext_vector_type(4))) float f32x4;

__device__ inline unsigned short f2bf(float x) {
    union { float f; unsigned u; } v; v.f = x;
    unsigned r = v.u + 0x7fff + ((v.u >> 16) & 1);   // RTNE
    return (unsigned short)(r >> 16);
}

__global__ void scatter_kernel(const int* __restrict__ pos,
                               int* __restrict__ table, int N) {
    int i = blockIdx.x * blockDim.x + threadIdx.x;
    if (i >= N) return;
    int x = pos[3 * i], y = pos[3 * i + 1], z = pos[3 * i + 2];
    // numpy duplicate semantics: last write (max index) wins
    atomicMax(&table[(x * GRID + y) * GRID + z], i);
}

// wt [27][ci][co] fp32 -> wtT [27][co][ci] bf16
__global__ void convert_wt(const float* __restrict__ wt,
                           unsigned short* __restrict__ wtT) {
    int t = blockIdx.x * 256 + threadIdx.x;
    if (t >= NOFF * CIN * COUT) return;
    int k = t >> 10, r = t & 1023, ci = r >> 5, co = r & 31;
    wtT[k * 1024 + co * 32 + ci] = f2bf(wt[t]);
}

// feats fp32 [N*32] -> bf16, packed pair writes (uint2 per 4 elems)
__global__ void convert_feats(const float* __restrict__ f,
                              unsigned* __restrict__ fb, int elems4) {
    int i = blockIdx.x * blockDim.x + threadIdx.x;
    if (i >= elems4) return;
    float4 v = *(const float4*)(f + 4 * (size_t)i);
    unsigned lo = (unsigned)f2bf(v.x) | ((unsigned)f2bf(v.y) << 16);
    unsigned hi = (unsigned)f2bf(v.z) | ((unsigned)f2bf(v.w) << 16);
    uint2 o; o.x = lo; o.y = hi;
    *(uint2*)(fb + 2 * (size_t)i) = o;
}

__global__ __launch_bounds__(256, 5)
void conv_kernel(const unsigned short* __restrict__ featsB,
                 const int* __restrict__ pos,
                 const unsigned short* __restrict__ wtT,
                 const int* __restrict__ table,
                 float* __restrict__ out, int N, int numTiles) {
    int gtid = blockIdx.x * 256 + threadIdx.x;
    int tile = gtid >> 6;               // one wave per 16-point tile
    if (tile >= numTiles) return;
    int lane = threadIdx.x & 63;
    int m = lane & 15, quad = lane >> 4;
    int base = tile * TILE;
    int g = base + m;
    bool gv = g < N;

    int x = 0, y = 0, z = 0;
    if (gv) { x = pos[3 * g]; y = pos[3 * g + 1]; z = pos[3 * g + 2]; }

    f32x4 acc0 = {0.f, 0.f, 0.f, 0.f};
    f32x4 acc1 = {0.f, 0.f, 0.f, 0.f};
    const unsigned short* wb = wtT + quad * 8;   // + k*1024 + co*32

#pragma unroll
    for (int k = 0; k < NOFF; ++k) {
        const int dx = k / 9 - 1, dy = (k / 3) % 3 - 1, dz = k % 3 - 1;
        int nx = x + dx, ny = y + dy, nz = z + dz;
        int id = -1;
        if (gv && (unsigned)nx < GRID && (unsigned)ny < GRID && (unsigned)nz < GRID)
            id = table[(nx * GRID + ny) * GRID + nz];

        bf16x8 a = {0, 0, 0, 0, 0, 0, 0, 0};
        if (id >= 0)
            a = *(const bf16x8*)(featsB + (size_t)id * CIN + quad * 8);

        bf16x8 b0 = *(const bf16x8*)(wb + k * 1024 + m * 32);
        bf16x8 b1 = *(const bf16x8*)(wb + k * 1024 + (m + 16) * 32);

        acc0 = __builtin_amdgcn_mfma_f32_16x16x32_bf16(a, b0, acc0, 0, 0, 0);
        acc1 = __builtin_amdgcn_mfma_f32_16x16x32_bf16(a, b1, acc1, 0, 0, 0);
    }

    // D layout: col = lane&15 = co, row = quad*4 + i = point within tile
#pragma unroll
    for (int i = 0; i < 4; ++i) {
        int go = base + quad * 4 + i;
        if (go < N) {
            out[(size_t)go * COUT + m]      = acc0[i];
            out[(size_t)go * COUT + m + 16] = acc1[i];
        }
    }
}

extern "C" void kernel_launch(void* const* d_in, const int* in_sizes, int n_in,
                              void* d_out, int out_size, void* d_ws, size_t ws_size,
                              hipStream_t stream) {
    const float* feats = (const float*)d_in[0];   // [N, 32]
    const int*   pos   = (const int*)d_in[1];     // [N, 3]
    const float* wt    = (const float*)d_in[2];   // [27, 32, 32]
    float* out = (float*)d_out;                   // [N, 32]
    int N = in_sizes[0] / CIN;

    char* ws = (char*)d_ws;
    int* table = (int*)ws;                                    // 8 MB
    size_t table_bytes = (size_t)GRID * GRID * GRID * sizeof(int);
    unsigned short* wtT = (unsigned short*)(ws + table_bytes);          // 55296 B
    unsigned short* featsB = (unsigned short*)(ws + table_bytes + 65536); // 32 MB

    hipMemsetAsync(table, 0xFF, table_bytes, stream);

    int sb = 256;
    scatter_kernel<<<(N + sb - 1) / sb, sb, 0, stream>>>(pos, table, N);

    int wtElems = NOFF * CIN * COUT;
    convert_wt<<<(wtElems + 255) / 256, 256, 0, stream>>>(wt, wtT);

    int elems4 = N * CIN / 4;
    convert_feats<<<(elems4 + 255) / 256, 256, 0, stream>>>(
        feats, (unsigned*)featsB, elems4);

    int numTiles = (N + TILE - 1) / TILE;
    int waves = numTiles;
    int blocks = (waves + 3) / 4;       // 4 waves (256 threads) per block
    conv_kernel<<<blocks, 256, 0, stream>>>(featsB, pos, wtT, table, out, N, numTiles);
}